// Round 3
// baseline (231.712 us; speedup 1.0000x reference)
//
#include <hip/hip_runtime.h>
#include <hip/hip_bf16.h>

#define BATCH  4096
#define UNITS  1024
#define CDIM   2048   // K = UNITS + IN_DIM
#define NDIM   4096   // 4 * UNITS (f, i, c, o)

typedef __attribute__((ext_vector_type(8))) short bf16x8;
typedef __attribute__((ext_vector_type(4))) float f32x4;

__device__ __forceinline__ void gload_lds16(const void* g, void* l) {
    __builtin_amdgcn_global_load_lds(
        (const __attribute__((address_space(1))) unsigned int*)g,
        (__attribute__((address_space(3))) unsigned int*)l, 16, 0, 0);
}

__device__ __forceinline__ float sigm(float x) { return 1.f / (1.f + __expf(-x)); }
__device__ __forceinline__ float tanh_fast(float x) { return 2.f / (1.f + __expf(-2.f * x)) - 1.f; }

// ---- prep: concat-cast x AND transpose-cast-permute weights in one launch ---
// Wt row layout (gate-interleaved, 128-periodic):
//   n(u,g) = (u>>5)*128 + ((u>>4)&1)*64 + g*16 + (u&15)
__global__ void prep(const float* __restrict__ h, const float* __restrict__ in,
                     const float* __restrict__ Wf, const float* __restrict__ Wi,
                     const float* __restrict__ Wc, const float* __restrict__ Wo,
                     __hip_bfloat16* __restrict__ x, __hip_bfloat16* __restrict__ Wt) {
    __shared__ float tile[32][33];
    int b = blockIdx.x, tid = threadIdx.x;
    if (b < (BATCH * CDIM / 4) / 256) {
        // concat(hidden, inputs) -> bf16 x [BATCH, CDIM]
        int t = b * 256 + tid;
        int col = (t % (CDIM / 4)) * 4;
        int row = t / (CDIM / 4);
        const float* src = (col < UNITS) ? (h + (size_t)row * UNITS + col)
                                         : (in + (size_t)row * UNITS + (col - UNITS));
        float4 v = *(const float4*)src;
        __hip_bfloat16* dst = x + (size_t)row * CDIM + col;
        dst[0] = __float2bfloat16(v.x); dst[1] = __float2bfloat16(v.y);
        dst[2] = __float2bfloat16(v.z); dst[3] = __float2bfloat16(v.w);
    } else {
        // transpose-cast W_g[CDIM, UNITS] -> permuted Wt[NDIM, CDIM]
        int idx = b - 8192;
        int g = idx >> 11, rest = idx & 2047, ky = rest >> 5, ux = rest & 31;
        const float* W = (g == 0) ? Wf : (g == 1) ? Wi : (g == 2) ? Wc : Wo;
        int u0 = ux * 32, k0 = ky * 32;
        int tx = tid & 31, ty = tid >> 5;          // (32, 8)
#pragma unroll
        for (int r = 0; r < 4; ++r)
            tile[ty + r * 8][tx] = W[(size_t)(k0 + ty + r * 8) * UNITS + u0 + tx];
        __syncthreads();
#pragma unroll
        for (int r = 0; r < 4; ++r) {
            int u = u0 + ty + r * 8;
            int n = ((u >> 5) << 7) + (((u >> 4) & 1) << 6) + (g << 4) + (u & 15);
            Wt[(size_t)n * CDIM + k0 + tx] = __float2bfloat16(tile[tx][ty + r * 8]);
        }
    }
}

// ---- fused GEMM + LSTM gates, 256x256 tile ----------------------------------
// 512 threads = 8 waves, each 64m x 128n (4x8 j-tiles of 16x16x32 MFMA).
// BK=32, double-buffered LDS (2x32KB), XOR-swizzled chunks (conflict-free),
// XCD patch swizzle (4mi x 8ni per XCD), fused LSTM epilogue.
__global__ __launch_bounds__(512, 2) void gemm_lstm(
    const __hip_bfloat16* __restrict__ A,    // [BATCH, CDIM]
    const __hip_bfloat16* __restrict__ Bt,   // [NDIM, CDIM], gate-interleaved rows
    const float* __restrict__ b_f, const float* __restrict__ b_i,
    const float* __restrict__ b_c, const float* __restrict__ b_o,
    const float* __restrict__ cell,          // [BATCH, UNITS]
    float* __restrict__ out)                 // [2, BATCH, UNITS]: hidden, cell
{
    __shared__ short As[2][256 * 32];
    __shared__ short Bs[2][256 * 32];
    const int K = CDIM;

    // XCD patch swizzle: xcd = bid%8 (round-robin heuristic); each XCD gets a
    // 4mi x 8ni patch -> per-k-slice working set ~192KB, L2-resident.
    int bid  = blockIdx.x;
    int xcd  = bid & 7, slot = bid >> 3;
    int mi   = (xcd & 3) * 4 + (slot & 3);
    int ni   = (xcd >> 2) * 8 + (slot >> 2);
    int m0   = mi * 256, n0 = ni * 256;

    int tid  = threadIdx.x;
    int w    = tid >> 6, lane = tid & 63;
    int quad = lane >> 4, r16 = lane & 15;
    int wm   = (w & 3) * 64;        // wave m-band
    int wc   = w >> 2;              // wave n-half (0/1)
    int wn   = wc * 128;

    f32x4 acc[4][8];
#pragma unroll
    for (int i = 0; i < 4; ++i)
#pragma unroll
        for (int j = 0; j < 8; ++j) acc[i][j] = (f32x4){0.f, 0.f, 0.f, 0.f};

    const short* Ag = (const short*)A  + (size_t)m0 * K;
    const short* Bg = (const short*)Bt + (size_t)n0 * K;

    // stage one 256x32 bf16 tile pair into buffer p (swizzled: LDS chunk c
    // holds global chunk c ^ (row&3))
    auto stage = [&](int p, int k0) {
#pragma unroll
        for (int q = 0; q < 2; ++q) {
            int s    = q * 512 + tid;          // chunk slot: row = s>>2, c = s&3
            int row  = s >> 2;
            int cg   = (s & 3) ^ (row & 3);
            int lofs = (q * 512 + w * 64) * 8; // wave-uniform LDS base (shorts)
            gload_lds16(Ag + (size_t)row * K + k0 + cg * 8, &As[p][lofs]);
            gload_lds16(Bg + (size_t)row * K + k0 + cg * 8, &Bs[p][lofs]);
        }
    };

    stage(0, 0);
    int kofs = (quad ^ (r16 & 3)) * 8;         // swizzled k-chunk (shorts)

    for (int kt = 0; kt < K / 32; ++kt) {
        int p = kt & 1;
        asm volatile("s_waitcnt vmcnt(0)" ::: "memory");
        __syncthreads();                       // buf p ready; buf 1-p consumed
        if (kt + 1 < K / 32) stage(1 - p, (kt + 1) * 32);

        bf16x8 af[4], bb[8];
#pragma unroll
        for (int i = 0; i < 4; ++i)
            af[i] = *(const bf16x8*)&As[p][(wm + i * 16 + r16) * 32 + kofs];
#pragma unroll
        for (int j = 0; j < 8; ++j)
            bb[j] = *(const bf16x8*)&Bs[p][(wn + j * 16 + r16) * 32 + kofs];
#pragma unroll
        for (int i = 0; i < 4; ++i)
#pragma unroll
            for (int j = 0; j < 8; ++j)
                acc[i][j] = __builtin_amdgcn_mfma_f32_16x16x32_bf16(af[i], bb[j], acc[i][j], 0, 0, 0);
    }

    // ---- fused epilogue: j-tile j = (grp = j>>2, gate = j&3) at
    // u = ni*64 + wc*32 + grp*16 + r16.  C/D: col=lane&15, row=quad*4+reg.
    float* out_h = out;
    float* out_c = out + (size_t)BATCH * UNITS;
    int ub = ni * 64 + wc * 32 + r16;
#pragma unroll
    for (int grp = 0; grp < 2; ++grp) {
        int u = ub + grp * 16;
        float bfv = b_f[u], biv = b_i[u], bcv = b_c[u], bov = b_o[u];
#pragma unroll
        for (int i = 0; i < 4; ++i) {
#pragma unroll
            for (int rr = 0; rr < 4; ++rr) {
                int m = m0 + wm + i * 16 + quad * 4 + rr;
                float fg = sigm(acc[i][grp * 4 + 0][rr] + bfv);
                float ig = sigm(acc[i][grp * 4 + 1][rr] + biv);
                float cc = tanh_fast(acc[i][grp * 4 + 2][rr] + bcv);
                float og = sigm(acc[i][grp * 4 + 3][rr] + bov);
                float cold = cell[(size_t)m * UNITS + u];
                float cn = fg * cold + ig * cc;
                out_h[(size_t)m * UNITS + u] = og * tanh_fast(cn);
                out_c[(size_t)m * UNITS + u] = cn;
            }
        }
    }
}

extern "C" void kernel_launch(void* const* d_in, const int* in_sizes, int n_in,
                              void* d_out, int out_size, void* d_ws, size_t ws_size,
                              hipStream_t stream) {
    const float* inputs = (const float*)d_in[0];
    const float* hidden = (const float*)d_in[1];
    const float* cell   = (const float*)d_in[2];
    const float* Wf = (const float*)d_in[3];
    const float* bf_ = (const float*)d_in[4];
    const float* Wi = (const float*)d_in[5];
    const float* bi_ = (const float*)d_in[6];
    const float* Wc = (const float*)d_in[7];
    const float* bc_ = (const float*)d_in[8];
    const float* Wo = (const float*)d_in[9];
    const float* bo_ = (const float*)d_in[10];
    float* out = (float*)d_out;

    char* ws = (char*)d_ws;
    __hip_bfloat16* x  = (__hip_bfloat16*)ws;                  // 16 MB
    __hip_bfloat16* Wt = (__hip_bfloat16*)(ws + (16u << 20));  // 16 MB

    // 1) concat-cast x (8192 blocks) + transpose-cast-permute W (8192 blocks)
    prep<<<dim3(16384), dim3(256), 0, stream>>>(hidden, inputs, Wf, Wi, Wc, Wo, x, Wt);
    // 2) fused 4-gate 256x256-tile GEMM + LSTM gate math (256 blocks = 1/CU)
    gemm_lstm<<<dim3(256), dim3(512), 0, stream>>>(
        x, Wt, bf_, bi_, bc_, bo_, cell, out);
}

// Round 4
// 219.822 us; speedup vs baseline: 1.0541x; 1.0541x over previous
//
#include <hip/hip_runtime.h>
#include <hip/hip_bf16.h>

#define BATCH  4096
#define UNITS  1024
#define CDIM   2048   // K = UNITS + IN_DIM
#define NDIM   4096   // 4 * UNITS (f, i, c, o)

typedef __attribute__((ext_vector_type(8))) short bf16x8;
typedef __attribute__((ext_vector_type(4))) float f32x4;

__device__ __forceinline__ void gload_lds16(const void* g, void* l) {
    __builtin_amdgcn_global_load_lds(
        (const __attribute__((address_space(1))) unsigned int*)g,
        (__attribute__((address_space(3))) unsigned int*)l, 16, 0, 0);
}

__device__ __forceinline__ float sigm(float x) { return 1.f / (1.f + __expf(-x)); }
__device__ __forceinline__ float tanh_fast(float x) { return 2.f / (1.f + __expf(-2.f * x)) - 1.f; }

// ---- prep: concat-cast x AND transpose-cast-permute weights in one launch ---
// Wt row layout (gate-interleaved, 128-periodic):
//   n(u,g) = (u>>5)*128 + ((u>>4)&1)*64 + g*16 + (u&15)
__global__ void prep(const float* __restrict__ h, const float* __restrict__ in,
                     const float* __restrict__ Wf, const float* __restrict__ Wi,
                     const float* __restrict__ Wc, const float* __restrict__ Wo,
                     __hip_bfloat16* __restrict__ x, __hip_bfloat16* __restrict__ Wt) {
    __shared__ float tile[32][33];
    int b = blockIdx.x, tid = threadIdx.x;
    if (b < (BATCH * CDIM / 4) / 256) {
        // concat(hidden, inputs) -> bf16 x [BATCH, CDIM]
        int t = b * 256 + tid;
        int col = (t % (CDIM / 4)) * 4;
        int row = t / (CDIM / 4);
        const float* src = (col < UNITS) ? (h + (size_t)row * UNITS + col)
                                         : (in + (size_t)row * UNITS + (col - UNITS));
        float4 v = *(const float4*)src;
        __hip_bfloat16* dst = x + (size_t)row * CDIM + col;
        dst[0] = __float2bfloat16(v.x); dst[1] = __float2bfloat16(v.y);
        dst[2] = __float2bfloat16(v.z); dst[3] = __float2bfloat16(v.w);
    } else {
        // transpose-cast W_g[CDIM, UNITS] -> permuted Wt[NDIM, CDIM]
        int idx = b - 8192;
        int g = idx >> 11, rest = idx & 2047, ky = rest >> 5, ux = rest & 31;
        const float* W = (g == 0) ? Wf : (g == 1) ? Wi : (g == 2) ? Wc : Wo;
        int u0 = ux * 32, k0 = ky * 32;
        int tx = tid & 31, ty = tid >> 5;          // (32, 8)
#pragma unroll
        for (int r = 0; r < 4; ++r)
            tile[ty + r * 8][tx] = W[(size_t)(k0 + ty + r * 8) * UNITS + u0 + tx];
        __syncthreads();
#pragma unroll
        for (int r = 0; r < 4; ++r) {
            int u = u0 + ty + r * 8;
            int n = ((u >> 5) << 7) + (((u >> 4) & 1) << 6) + (g << 4) + (u & 15);
            Wt[(size_t)n * CDIM + k0 + tx] = __float2bfloat16(tile[tx][ty + r * 8]);
        }
    }
}

// ---- flatmm-style fused GEMM + LSTM gates -----------------------------------
// Block 128m x 256n, 256 threads = 4 waves; wave = 128m x 64n (8i x 4j MFMA).
// A staged via global_load_lds (BK=64, r2-proven xor8 swizzle, double-buffered);
// B streamed L2 -> VGPR with 1-deep register prefetch (no LDS, no barrier dep).
// 512 blocks = 2/CU for inter-block TLP. Fused LSTM epilogue.
__global__ __launch_bounds__(256, 2) void gemm_lstm(
    const __hip_bfloat16* __restrict__ A,    // [BATCH, CDIM] bf16
    const __hip_bfloat16* __restrict__ Bt,   // [NDIM, CDIM] bf16, gate-interleaved
    const float* __restrict__ b_f, const float* __restrict__ b_i,
    const float* __restrict__ b_c, const float* __restrict__ b_o,
    const float* __restrict__ cell,          // [BATCH, UNITS]
    float* __restrict__ out)                 // [2, BATCH, UNITS]: hidden, cell
{
    __shared__ short As[2][128 * 64];        // 2 x 16 KB, rows of 128 B
    const int K = CDIM;

    // XCD swizzle: xcd = bid&7 gets n-slice of 512 (2 nb) -> B slice 2 MB, L2-resident
    int bid = blockIdx.x;
    int nb  = (bid & 7) * 2 + ((bid >> 3) & 1);
    int mb  = bid >> 4;
    int m0  = mb * 128, n0 = nb * 256;

    int tid  = threadIdx.x;
    int w    = tid >> 6, lane = tid & 63;
    int quad = lane >> 4, r16 = lane & 15;
    int wn   = w * 64;

    f32x4 acc[8][4];
#pragma unroll
    for (int i = 0; i < 8; ++i)
#pragma unroll
        for (int j = 0; j < 4; ++j) acc[i][j] = (f32x4){0.f, 0.f, 0.f, 0.f};

    const short* Ag = (const short*)A  + (size_t)m0 * K;
    // per-lane B base: row n0+wn+j*16+r16, chunk quad
    const short* Bg = (const short*)Bt + (size_t)(n0 + wn + r16) * K + quad * 8;

    auto stageA = [&](int p, int k0) {
#pragma unroll
        for (int q = 0; q < 4; ++q) {
            int s    = q * 256 + tid;          // 1024 slots of 16B = 128 rows x 128B
            int row  = s >> 3;
            int cg   = (s & 7) ^ (row & 7);    // swizzled global chunk (r2-proven)
            int lofs = (q * 256 + w * 64) * 8; // wave-uniform LDS base (shorts)
            gload_lds16(Ag + (size_t)row * K + k0 + cg * 8, &As[p][lofs]);
        }
    };

    bf16x8 bcur[8], bnxt[8];
#pragma unroll
    for (int ks = 0; ks < 2; ++ks)
#pragma unroll
        for (int j = 0; j < 4; ++j)
            bcur[ks * 4 + j] = *(const bf16x8*)&Bg[(size_t)(j * 16) * K + ks * 32];
    stageA(0, 0);

    for (int kt = 0; kt < K / 64; ++kt) {
        int p = kt & 1;
        asm volatile("s_waitcnt vmcnt(0)" ::: "memory");  // A(kt) in LDS, B(kt) in regs
        __syncthreads();
        if (kt + 1 < K / 64) {
            stageA(1 - p, (kt + 1) * 64);                 // overlap compute below
            int kb = (kt + 1) * 64;
#pragma unroll
            for (int ks = 0; ks < 2; ++ks)
#pragma unroll
                for (int j = 0; j < 4; ++j)
                    bnxt[ks * 4 + j] = *(const bf16x8*)&Bg[(size_t)(j * 16) * K + kb + ks * 32];
        }
#pragma unroll
        for (int ks = 0; ks < 2; ++ks) {
            bf16x8 af[8];
            int kc = ((quad + ks * 4) ^ (r16 & 7)) * 8;
#pragma unroll
            for (int i = 0; i < 8; ++i)
                af[i] = *(const bf16x8*)&As[p][(i * 16 + r16) * 64 + kc];
#pragma unroll
            for (int i = 0; i < 8; ++i)
#pragma unroll
                for (int j = 0; j < 4; ++j)
                    acc[i][j] = __builtin_amdgcn_mfma_f32_16x16x32_bf16(af[i], bcur[ks * 4 + j], acc[i][j], 0, 0, 0);
        }
#pragma unroll
        for (int t = 0; t < 8; ++t) bcur[t] = bnxt[t];
    }

    // ---- fused LSTM epilogue: j = gate, u = nb*64 + (w>>1)*32 + (w&1)*16 + r16
    // C/D layout: col=lane&15, row=quad*4+reg (m89-verified)
    int u = nb * 64 + (w >> 1) * 32 + (w & 1) * 16 + r16;
    float bfv = b_f[u], biv = b_i[u], bcv = b_c[u], bov = b_o[u];
    float* out_h = out;
    float* out_c = out + (size_t)BATCH * UNITS;
#pragma unroll
    for (int i = 0; i < 8; ++i) {
#pragma unroll
        for (int rr = 0; rr < 4; ++rr) {
            int m = m0 + i * 16 + quad * 4 + rr;
            float fg = sigm(acc[i][0][rr] + bfv);
            float ig = sigm(acc[i][1][rr] + biv);
            float cc = tanh_fast(acc[i][2][rr] + bcv);
            float og = sigm(acc[i][3][rr] + bov);
            float cold = cell[(size_t)m * UNITS + u];
            float cn = fg * cold + ig * cc;
            out_h[(size_t)m * UNITS + u] = og * tanh_fast(cn);
            out_c[(size_t)m * UNITS + u] = cn;
        }
    }
}

extern "C" void kernel_launch(void* const* d_in, const int* in_sizes, int n_in,
                              void* d_out, int out_size, void* d_ws, size_t ws_size,
                              hipStream_t stream) {
    const float* inputs = (const float*)d_in[0];
    const float* hidden = (const float*)d_in[1];
    const float* cell   = (const float*)d_in[2];
    const float* Wf = (const float*)d_in[3];
    const float* bf_ = (const float*)d_in[4];
    const float* Wi = (const float*)d_in[5];
    const float* bi_ = (const float*)d_in[6];
    const float* Wc = (const float*)d_in[7];
    const float* bc_ = (const float*)d_in[8];
    const float* Wo = (const float*)d_in[9];
    const float* bo_ = (const float*)d_in[10];
    float* out = (float*)d_out;

    char* ws = (char*)d_ws;
    __hip_bfloat16* x  = (__hip_bfloat16*)ws;                  // 16 MB
    __hip_bfloat16* Wt = (__hip_bfloat16*)(ws + (16u << 20));  // 16 MB

    // 1) concat-cast x (8192 blocks) + transpose-cast-permute W (8192 blocks)
    prep<<<dim3(16384), dim3(256), 0, stream>>>(hidden, inputs, Wf, Wi, Wc, Wo, x, Wt);
    // 2) flatmm-style fused 4-gate GEMM + LSTM gates (512 blocks = 2/CU)
    gemm_lstm<<<dim3(512), dim3(256), 0, stream>>>(
        x, Wt, bf_, bi_, bc_, bo_, cell, out);
}